// Round 9
// baseline (974.903 us; speedup 1.0000x reference)
//
#include <hip/hip_runtime.h>
#include <stdint.h>

#define TSTEPS 1000
#define NB 256
#define NF 64
#define NH 256   // H1 == H2 == 256
#define CHUNK 8
#define NCH 125  // 125 * 8 == 1000, no tail

// Prep: transpose W2 (H2,H1) -> W2T[h1][h2] in d_ws for coalesced gathers,
// and zero the two global spike counters.
__global__ void snn_prep(const float* __restrict__ W2, float* __restrict__ W2T,
                         unsigned int* __restrict__ counts) {
    int idx = blockIdx.x * 256 + threadIdx.x;     // idx = h1*256 + h2
    W2T[idx] = W2[(idx & 255) * 256 + (idx >> 8)];
    if (idx < 2) counts[idx] = 0u;
}

// float4 component by literal index (folds at -O3 after unrolling; avoids
// address-of-local which would defeat SROA).
#define F4C(v, jj) ((jj) == 0 ? (v).x : (jj) == 1 ? (v).y : (jj) == 2 ? (v).z : (v).w)

// Consumer step: read the 5 metadata words (named locals), branch-free
// first-4 gather with value masking (order matches the guarded loop
// exactly), rare overflow path, mem2 update.
#define CSTEP(cb, tt) do {                                                    \
    unsigned int cwv = *(const unsigned int*)&scnt8[cb][(tt) * 4];            \
    unsigned int u0 = *(const unsigned int*)&slist[cb][tt][0];                \
    unsigned int u1 = *(const unsigned int*)&slist[cb][tt][64];               \
    unsigned int u2 = *(const unsigned int*)&slist[cb][tt][128];              \
    unsigned int u3 = *(const unsigned int*)&slist[cb][tt][192];              \
    int c0 = (int)(cwv & 255u),        c1 = (int)((cwv >> 8) & 255u);         \
    int c2 = (int)((cwv >> 16) & 255u), c3 = (int)((cwv >> 24) & 255u);       \
    float q0 = 0.f, q1 = 0.f, q2 = 0.f, q3 = 0.f;                             \
    _Pragma("unroll")                                                         \
    for (int i = 0; i < 4; ++i) {                                             \
        float v0 = W2Th[(int)((u0 >> (8 * i)) & 255u) << 8];                  \
        float v1 = W2Th[(int)((u1 >> (8 * i)) & 255u) << 8];                  \
        float v2 = W2Th[(int)((u2 >> (8 * i)) & 255u) << 8];                  \
        float v3 = W2Th[(int)((u3 >> (8 * i)) & 255u) << 8];                  \
        q0 += (i < c0) ? v0 : 0.f;                                            \
        q1 += (i < c1) ? v1 : 0.f;                                            \
        q2 += (i < c2) ? v2 : 0.f;                                            \
        q3 += (i < c3) ? v3 : 0.f;                                            \
    }                                                                         \
    int nmax = max(max(c0, c1), max(c2, c3));                                 \
    if (nmax > 4) {   /* rare overflow path (per-wave spike count > 4) */     \
        const unsigned char* sl = &slist[cb][tt][0];                          \
        for (int i = 4; i < nmax; ++i) {                                      \
            if (i < c0) q0 += W2Th[(int)sl[i] << 8];                          \
            if (i < c1) q1 += W2Th[(int)sl[64 + i] << 8];                     \
            if (i < c2) q2 += W2Th[(int)sl[128 + i] << 8];                    \
            if (i < c3) q3 += W2Th[(int)sl[192 + i] << 8];                    \
        }                                                                     \
    }                                                                         \
    float cur2 = b2h + ((q0 + q1) + (q2 + q3));                               \
    float reset2 = (mem2 > 1.f) ? 1.f : 0.f;                                  \
    mem2 = 0.9048374180359595f * mem2 + cur2 - reset2; /* beta2=exp(-1/10) */ \
    bool s2 = (mem2 - 1.f) > 0.f;                                             \
    cnt2 += (int)s2;                                                          \
    mem2s += mem2;                                                            \
} while (0)

// Main: one 512-thread workgroup per batch, wave-specialized pipeline.
//   waves 0-3 (producer): own mem1[h], layer 1 for chunk c -> slist[c&1].
//   waves 4-7 (consumer): own mem2[h], layer 2 for chunk c-1.
// Producer layer 1: dense FMA with W1 from LDS, f-loop OUTER so each
// W1T[f][h] ds_read is amortized over 8 timesteps (8-way ILP hides LDS
// latency; fixed trip count -> fully unrolled/pipelined). Round-8 lesson:
// the sparse ctz-gather's data-dependent while loop serialized on LDS
// latency (913us); rounds 1-7: per-thread W1 registers are always
// rematerialized by the backend (VGPR stuck at 52-88).
__launch_bounds__(512, 2)
__global__ void snn_main(const float* __restrict__ spikes,
                         const float* __restrict__ W1,
                         const float* __restrict__ b1,
                         const float* __restrict__ W2T,
                         const float* __restrict__ b2,
                         const float* __restrict__ Wr,
                         const float* __restrict__ br,
                         float* __restrict__ out,
                         unsigned int* __restrict__ counts) {
    const int b = blockIdx.x;
    const int tid = threadIdx.x;
    const int lane = tid & 63;
    const int wv = tid >> 6;          // 0..7
    const bool producer = (wv < 4);
    const int h = tid & 255;          // hidden index within the role group

    __shared__ float W1T[NF][NH + 1];              // +1 pad
    __shared__ unsigned char slist[2][CHUNK][256]; // per-chunk-buf spk1 lists
    __shared__ unsigned char scnt8[2][CHUNK * 4];  // per-step per-wave counts
    __shared__ float rp0[4], rp1[4];
    __shared__ int rc1[4], rc2[4];

    const size_t xstride = (size_t)NB * NF;
    const float* xrow_base = spikes + (size_t)b * NF;     // uniform row base
    const float* xbase = xrow_base + lane;                // per-lane warm ptr
    const float* W2Th = W2T + h;

    // Cooperative staging: W1T[f][h1] = W1[h1*64+f]. Coalesced global reads;
    // conflict-free LDS writes (bank varies with f).
    for (int i = tid; i < NH * NF; i += 512) {
        W1T[i & 63][i >> 6] = W1[i];
    }

    float mem1 = 0.f, mem2 = 0.f, mem2s = 0.f;
    int cnt1 = 0, cnt2 = 0;
    float b1h = 0.f, b2h = 0.f;

    if (producer) {
        b1h = b1[h];
        // warm chunk-0 x rows into L1 (per-lane coalesced, one lane per feature)
        float wm0 = xbase[0],           wm1 = xbase[xstride];
        float wm2 = xbase[2 * xstride], wm3 = xbase[3 * xstride];
        float wm4 = xbase[4 * xstride], wm5 = xbase[5 * xstride];
        float wm6 = xbase[6 * xstride], wm7 = xbase[7 * xstride];
        float ws = ((wm0 + wm1) + (wm2 + wm3)) + ((wm4 + wm5) + (wm6 + wm7));
        asm volatile("" :: "v"(ws));
    } else {
        b2h = b2[h];
    }
    __syncthreads();   // W1T staged and visible to producer waves

    for (int c = 0; c < NCH; ++c) {
        if (producer) {
            const int pb = c & 1;
            const int tb = c * CHUNK;
            // ---- layer 1: dense FMA, f outer / t inner ----
            // 4 accumulator chains per step (f 0-15,16-31,32-47,48-63,
            // ascending within each) — bit-exact order match to all
            // previous passing rounds; fma(0,w,a)=a, fma(1,w,a)=round(a+w).
            float a[CHUNK][4] = {};
            #pragma unroll
            for (int fb = 0; fb < 8; ++fb) {
                // uniform x block: features fb*8..fb*8+7 for all 8 steps
                float4 xa[CHUNK], xb[CHUNK];
                #pragma unroll
                for (int t = 0; t < CHUNK; ++t) {
                    const float* xr =
                        xrow_base + (size_t)(tb + t) * xstride + fb * 8;
                    xa[t] = *(const float4*)xr;
                    xb[t] = *(const float4*)(xr + 4);
                }
                #pragma unroll
                for (int j = 0; j < 8; ++j) {
                    const int f = fb * 8 + j;
                    const int ch = f >> 4;          // compile-time constant
                    float w = W1T[f][h];            // 1 ds_read, 8 uses
                    #pragma unroll
                    for (int t = 0; t < CHUNK; ++t) {
                        float xv = (j < 4) ? F4C(xa[t], j) : F4C(xb[t], j - 4);
                        a[t][ch] += xv * w;
                    }
                }
            }
            // ---- step tails: serial mem1 recurrence + spk1 publish ----
            #pragma unroll
            for (int t = 0; t < CHUNK; ++t) {
                float cur1 = b1h + ((a[t][0] + a[t][1]) + (a[t][2] + a[t][3]));
                float reset1 = (mem1 > 1.f) ? 1.f : 0.f;
                mem1 = 0.8187307530779818f * mem1 + cur1 - reset1; // beta1
                bool s1 = (mem1 - 1.f) > 0.f;
                cnt1 += (int)s1;
                unsigned long long sm = __ballot(s1);
                if (lane == 0) scnt8[pb][t * 4 + wv] = (unsigned char)__popcll(sm);
                if (s1) {
                    int rank = __popcll(sm & ((1ull << lane) - 1ull));
                    slist[pb][t][(wv << 6) + rank] = (unsigned char)h;
                }
            }
            // warm next chunk's x rows (land during next chunk's compute)
            int cn = (c + 1 < NCH) ? c + 1 : 0;  // clamped dummy on last
            const float* xw = xbase + (size_t)cn * CHUNK * xstride;
            float wm0 = xw[0],           wm1 = xw[xstride];
            float wm2 = xw[2 * xstride], wm3 = xw[3 * xstride];
            float wm4 = xw[4 * xstride], wm5 = xw[5 * xstride];
            float wm6 = xw[6 * xstride], wm7 = xw[7 * xstride];
            float ws = ((wm0 + wm1) + (wm2 + wm3)) + ((wm4 + wm5) + (wm6 + wm7));
            asm volatile("" :: "v"(ws));
        } else if (c > 0) {
            const int cb = (c - 1) & 1;
            // ---- layer 2: CHUNK steps for chunk c-1 ----
            CSTEP(cb, 0); CSTEP(cb, 1); CSTEP(cb, 2); CSTEP(cb, 3);
            CSTEP(cb, 4); CSTEP(cb, 5); CSTEP(cb, 6); CSTEP(cb, 7);
        }
        __syncthreads();   // chunk handoff: slist[pb] ready; buffers swap
    }
    // pipeline epilogue: last chunk's layer 2
    if (!producer) {
        const int cb = (NCH - 1) & 1;
        CSTEP(cb, 0); CSTEP(cb, 1); CSTEP(cb, 2); CSTEP(cb, 3);
        CSTEP(cb, 4); CSTEP(cb, 5); CSTEP(cb, 6); CSTEP(cb, 7);
    }

    // readout: out[b,:] = (mem2_sum/T) @ Wr.T + br ; role-local reductions
    if (producer) {
        int rcs1 = cnt1;
        for (int off = 32; off > 0; off >>= 1) rcs1 += __shfl_down(rcs1, off);
        if (lane == 0) rc1[wv] = rcs1;
    } else {
        float v = mem2s / 1000.0f;
        float p0 = v * Wr[h];
        float p1 = v * Wr[NH + h];
        int rcs2 = cnt2;
        for (int off = 32; off > 0; off >>= 1) {
            p0 += __shfl_down(p0, off);
            p1 += __shfl_down(p1, off);
            rcs2 += __shfl_down(rcs2, off);
        }
        if (lane == 0) { rp0[wv - 4] = p0; rp1[wv - 4] = p1; rc2[wv - 4] = rcs2; }
    }
    __syncthreads();
    if (tid == 0) {
        out[2 * b]     = ((rp0[0] + rp0[1]) + (rp0[2] + rp0[3])) + br[0];
        out[2 * b + 1] = ((rp1[0] + rp1[1]) + (rp1[2] + rp1[3])) + br[1];
        atomicAdd(&counts[0], (unsigned)(rc1[0] + rc1[1] + rc1[2] + rc1[3]));
        atomicAdd(&counts[1], (unsigned)(rc2[0] + rc2[1] + rc2[2] + rc2[3]));
    }
}

__global__ void snn_finalize(const unsigned int* __restrict__ counts,
                             float* __restrict__ out) {
    if (threadIdx.x < 2)
        out[512 + threadIdx.x] = (float)counts[threadIdx.x] / 65536000.0f; // T*B*256
}

extern "C" void kernel_launch(void* const* d_in, const int* in_sizes, int n_in,
                              void* d_out, int out_size, void* d_ws, size_t ws_size,
                              hipStream_t stream) {
    const float* spikes = (const float*)d_in[0];
    const float* W1     = (const float*)d_in[1];
    const float* b1     = (const float*)d_in[2];
    const float* W2     = (const float*)d_in[3];
    const float* b2     = (const float*)d_in[4];
    const float* Wr     = (const float*)d_in[5];
    const float* br     = (const float*)d_in[6];
    float* out = (float*)d_out;

    float* W2T = (float*)d_ws;                                   // 256 KB
    unsigned int* counts = (unsigned int*)((char*)d_ws + (size_t)NH * NH * sizeof(float));

    snn_prep<<<256, 256, 0, stream>>>(W2, W2T, counts);
    snn_main<<<256, 512, 0, stream>>>(spikes, W1, b1, W2T, b2, Wr, br, out, counts);
    snn_finalize<<<1, 64, 0, stream>>>(counts, out);
}

// Round 10
// 894.402 us; speedup vs baseline: 1.0900x; 1.0900x over previous
//
#include <hip/hip_runtime.h>
#include <stdint.h>

#define TSTEPS 1000
#define NB 256
#define NF 64
#define NH 256   // H1 == H2 == 256
#define TSEG 250
#define NSEG 4   // 4 * 250 == 1000

// Workspace layout (bytes). CUR buffer is reused: A writes CUR1, B consumes
// it, C overwrites with CUR2, D consumes. Total ~74.9 MB.
#define CUR_BYTES ((size_t)TSEG * NB * NH * 4)          // 65,536,000
#define MSK_OFF   (CUR_BYTES)
#define MSK_BYTES ((size_t)TSTEPS * NB * 4 * 8)         // 8,192,000 (4 u64 per (t,b))
#define W2T_OFF   (MSK_OFF + MSK_BYTES)
#define W2T_BYTES ((size_t)NH * NH * 4)                 // 262,144
#define W1T_OFF   (W2T_OFF + W2T_BYTES)
#define W1T_BYTES ((size_t)NF * NH * 4)                 // 65,536
#define M1_OFF    (W1T_OFF + W1T_BYTES)
#define ST_BYTES  ((size_t)NB * NH * 4)                 // 262,144
#define M2_OFF    (M1_OFF + ST_BYTES)
#define M2S_OFF   (M2_OFF + ST_BYTES)
#define CNT_OFF   (M2S_OFF + ST_BYTES)

// Prep: W2T[h1][h2] transpose, W1Tg[f][h1] transpose, zero states/counters.
__global__ void snn_prep(const float* __restrict__ W1, const float* __restrict__ W2,
                         float* __restrict__ W2T, float* __restrict__ W1Tg,
                         float* __restrict__ m1st, float* __restrict__ m2st,
                         float* __restrict__ m2sst, unsigned int* __restrict__ counts) {
    int idx = blockIdx.x * 256 + threadIdx.x;            // [0, 65536)
    W2T[idx] = W2[(idx & 255) * 256 + (idx >> 8)];       // W2T[h1*256+h2] = W2[h2*256+h1]
    m1st[idx] = 0.f; m2st[idx] = 0.f; m2sst[idx] = 0.f;
    if (idx < NF * NH) W1Tg[(idx & 63) * 256 + (idx >> 6)] = W1[idx]; // W1Tg[f*256+h]=W1[h*64+f]
    if (idx < 2) counts[idx] = 0u;
}

// A: CUR1[t,b,h] = b1[h] + x[t,b,:]@W1[h,:] — fully parallel over (t,b).
// One wave per (t,b) pair (8 pairs per wave via k-loop to amortize the LDS
// staging of W1T). lane covers h = 4*lane..4*lane+3 via ds_read_b128.
// Sparse 4-chain ctz gather (f-quarters 0-15/16-31/32-47/48-63 ascending,
// (a0+a1)+(a2+a3) combine) — bit-exact order match to all passing rounds.
__launch_bounds__(256)
__global__ void snn_cur1(const float* __restrict__ spikes,
                         const float* __restrict__ W1Tg,
                         const float* __restrict__ b1,
                         float* __restrict__ CUR, int s) {
    const int tid = threadIdx.x;
    const int lane = tid & 63, wv = tid >> 6;
    __shared__ float W1T[NF][NH];     // 64 KB; [f][h]
    for (int i = tid; i < NF * NH; i += 256) W1T[i >> 8][i & 255] = W1Tg[i];
    __syncthreads();

    const float4 b1v = *(const float4*)&b1[4 * lane];
    const int pbase = (blockIdx.x * 4 + wv) * 8;
    for (int k = 0; k < 8; ++k) {
        const int p = pbase + k;
        const int b = p & 255, tl = p >> 8;
        float xv = spikes[((size_t)(s * TSEG + tl) * NB + b) * NF + lane];
        unsigned long long xm = __ballot(xv > 0.f);
        unsigned m0 = (unsigned)(xm & 0xFFFFull);
        unsigned m1 = (unsigned)((xm >> 16) & 0xFFFFull);
        unsigned m2 = (unsigned)((xm >> 32) & 0xFFFFull);
        unsigned m3 = (unsigned)((xm >> 48) & 0xFFFFull);
        float a00 = 0.f, a10 = 0.f, a20 = 0.f, a30 = 0.f;
        float a01 = 0.f, a11 = 0.f, a21 = 0.f, a31 = 0.f;
        float a02 = 0.f, a12 = 0.f, a22 = 0.f, a32 = 0.f;
        float a03 = 0.f, a13 = 0.f, a23 = 0.f, a33 = 0.f;
        while (m0 | m1 | m2 | m3) {
            if (m0) { int f = __builtin_ctz(m0); m0 &= m0 - 1;
                float4 v = *(const float4*)&W1T[f][4 * lane];
                a00 += v.x; a10 += v.y; a20 += v.z; a30 += v.w; }
            if (m1) { int f = __builtin_ctz(m1) + 16; m1 &= m1 - 1;
                float4 v = *(const float4*)&W1T[f][4 * lane];
                a01 += v.x; a11 += v.y; a21 += v.z; a31 += v.w; }
            if (m2) { int f = __builtin_ctz(m2) + 32; m2 &= m2 - 1;
                float4 v = *(const float4*)&W1T[f][4 * lane];
                a02 += v.x; a12 += v.y; a22 += v.z; a32 += v.w; }
            if (m3) { int f = __builtin_ctz(m3) + 48; m3 &= m3 - 1;
                float4 v = *(const float4*)&W1T[f][4 * lane];
                a03 += v.x; a13 += v.y; a23 += v.z; a33 += v.w; }
        }
        float4 o;
        o.x = b1v.x + ((a00 + a01) + (a02 + a03));
        o.y = b1v.y + ((a10 + a11) + (a12 + a13));
        o.z = b1v.z + ((a20 + a21) + (a22 + a23));
        o.w = b1v.w + ((a30 + a31) + (a32 + a33));
        *(float4*)&CUR[((size_t)tl * NB + b) * NH + 4 * lane] = o;
    }
}

// B: serial mem1 scan (streaming). Thread=(b,h); loads precomputed CUR1
// (coalesced, independent -> unroll-10 pipelines them), publishes spk1
// ballot masks to global (4 u64 per (t,b)).
__launch_bounds__(256)
__global__ void snn_scan1(const float* __restrict__ CUR,
                          float* __restrict__ m1st,
                          unsigned long long* __restrict__ masks,
                          unsigned int* __restrict__ counts, int s) {
    const int b = blockIdx.x, h = threadIdx.x;
    const int lane = h & 63, wv = h >> 6;
    float mem1 = (s == 0) ? 0.f : m1st[b * NH + h];
    int cnt1 = 0;
    const float* cp = CUR + (size_t)b * NH + h;
    unsigned long long* mp = masks + ((size_t)(s * TSEG) * NB + b) * 4 + wv;
    #pragma unroll 10
    for (int tl = 0; tl < TSEG; ++tl) {
        float cur1 = cp[(size_t)tl * (NB * NH)];
        float reset1 = (mem1 > 1.f) ? 1.f : 0.f;
        mem1 = 0.8187307530779818f * mem1 + cur1 - reset1;   // beta1 = exp(-1/5)
        bool s1 = (mem1 - 1.f) > 0.f;
        cnt1 += (int)s1;
        unsigned long long sm = __ballot(s1);
        if (lane == 0) mp[(size_t)tl * (NB * 4)] = sm;
    }
    m1st[b * NH + h] = mem1;
    for (int off = 32; off > 0; off >>= 1) cnt1 += __shfl_down(cnt1, off);
    if (lane == 0) atomicAdd(&counts[0], (unsigned)cnt1);
}

// C: CUR2[t,b,h2] = b2[h2] + sum over active h1 of W2T[h1][h2] — fully
// parallel over (t,b). One wave per (t,b); 4 chains = the 4 h1-groups
// (ascending h1 within each, (q0+q1)+(q2+q3)) — exact consumer order.
// W2T rows are L2-resident; no LDS -> 8 blocks/CU of TLP hides latency.
__launch_bounds__(256)
__global__ void snn_cur2(const unsigned long long* __restrict__ masks,
                         const float* __restrict__ W2T,
                         const float* __restrict__ b2,
                         float* __restrict__ CUR, int s) {
    const int tid = threadIdx.x;
    const int lane = tid & 63, wv = tid >> 6;
    const int p = blockIdx.x * 4 + wv;
    const int b = p & 255, tl = p >> 8;
    const unsigned long long* mp = masks + ((size_t)(s * TSEG + tl) * NB + b) * 4;
    unsigned long long m0 = mp[0], m1 = mp[1], m2 = mp[2], m3 = mp[3];
    float q00 = 0.f, q10 = 0.f, q20 = 0.f, q30 = 0.f;
    float q01 = 0.f, q11 = 0.f, q21 = 0.f, q31 = 0.f;
    float q02 = 0.f, q12 = 0.f, q22 = 0.f, q32 = 0.f;
    float q03 = 0.f, q13 = 0.f, q23 = 0.f, q33 = 0.f;
    const float* W2l = W2T + 4 * lane;
    while (m0 | m1 | m2 | m3) {
        if (m0) { int j = __builtin_ctzll(m0); m0 &= m0 - 1;
            float4 v = *(const float4*)(W2l + ((size_t)j << 8));
            q00 += v.x; q10 += v.y; q20 += v.z; q30 += v.w; }
        if (m1) { int j = __builtin_ctzll(m1); m1 &= m1 - 1;
            float4 v = *(const float4*)(W2l + ((size_t)(64 + j) << 8));
            q01 += v.x; q11 += v.y; q21 += v.z; q31 += v.w; }
        if (m2) { int j = __builtin_ctzll(m2); m2 &= m2 - 1;
            float4 v = *(const float4*)(W2l + ((size_t)(128 + j) << 8));
            q02 += v.x; q12 += v.y; q22 += v.z; q32 += v.w; }
        if (m3) { int j = __builtin_ctzll(m3); m3 &= m3 - 1;
            float4 v = *(const float4*)(W2l + ((size_t)(192 + j) << 8));
            q03 += v.x; q13 += v.y; q23 += v.z; q33 += v.w; }
    }
    const float4 b2v = *(const float4*)&b2[4 * lane];
    float4 o;
    o.x = b2v.x + ((q00 + q01) + (q02 + q03));
    o.y = b2v.y + ((q10 + q11) + (q12 + q13));
    o.z = b2v.z + ((q20 + q21) + (q22 + q23));
    o.w = b2v.w + ((q30 + q31) + (q32 + q33));
    *(float4*)&CUR[((size_t)tl * NB + b) * NH + 4 * lane] = o;
}

// D: serial mem2 scan (streaming) + readout on the last segment.
__launch_bounds__(256)
__global__ void snn_scan2(const float* __restrict__ CUR,
                          float* __restrict__ m2st, float* __restrict__ m2sst,
                          const float* __restrict__ Wr, const float* __restrict__ br,
                          float* __restrict__ out, unsigned int* __restrict__ counts,
                          int s) {
    const int b = blockIdx.x, h = threadIdx.x;
    const int lane = h & 63, wv = h >> 6;
    __shared__ float rp0[4], rp1[4];
    float mem2 = (s == 0) ? 0.f : m2st[b * NH + h];
    float m2s  = (s == 0) ? 0.f : m2sst[b * NH + h];
    int cnt2 = 0;
    const float* cp = CUR + (size_t)b * NH + h;
    #pragma unroll 10
    for (int tl = 0; tl < TSEG; ++tl) {
        float cur2 = cp[(size_t)tl * (NB * NH)];
        float reset2 = (mem2 > 1.f) ? 1.f : 0.f;
        mem2 = 0.9048374180359595f * mem2 + cur2 - reset2;   // beta2 = exp(-1/10)
        bool s2 = (mem2 - 1.f) > 0.f;
        cnt2 += (int)s2;
        m2s += mem2;
    }
    for (int off = 32; off > 0; off >>= 1) cnt2 += __shfl_down(cnt2, off);
    if (lane == 0) atomicAdd(&counts[1], (unsigned)cnt2);
    if (s < NSEG - 1) {
        m2st[b * NH + h] = mem2;
        m2sst[b * NH + h] = m2s;
    } else {
        // readout: out[b,:] = (mem2_sum/T) @ Wr.T + br (r0-verified reduction)
        float v = m2s / 1000.0f;
        float p0 = v * Wr[h];
        float p1 = v * Wr[NH + h];
        for (int off = 32; off > 0; off >>= 1) {
            p0 += __shfl_down(p0, off);
            p1 += __shfl_down(p1, off);
        }
        if (lane == 0) { rp0[wv] = p0; rp1[wv] = p1; }
        __syncthreads();
        if (h == 0) {
            out[2 * b]     = ((rp0[0] + rp0[1]) + (rp0[2] + rp0[3])) + br[0];
            out[2 * b + 1] = ((rp1[0] + rp1[1]) + (rp1[2] + rp1[3])) + br[1];
        }
    }
}

__global__ void snn_finalize(const unsigned int* __restrict__ counts,
                             float* __restrict__ out) {
    if (threadIdx.x < 2)
        out[512 + threadIdx.x] = (float)counts[threadIdx.x] / 65536000.0f; // T*B*256
}

extern "C" void kernel_launch(void* const* d_in, const int* in_sizes, int n_in,
                              void* d_out, int out_size, void* d_ws, size_t ws_size,
                              hipStream_t stream) {
    const float* spikes = (const float*)d_in[0];
    const float* W1     = (const float*)d_in[1];
    const float* b1     = (const float*)d_in[2];
    const float* W2     = (const float*)d_in[3];
    const float* b2     = (const float*)d_in[4];
    const float* Wr     = (const float*)d_in[5];
    const float* br     = (const float*)d_in[6];
    float* out = (float*)d_out;

    char* ws = (char*)d_ws;
    float* CUR = (float*)ws;
    unsigned long long* masks = (unsigned long long*)(ws + MSK_OFF);
    float* W2T   = (float*)(ws + W2T_OFF);
    float* W1Tg  = (float*)(ws + W1T_OFF);
    float* m1st  = (float*)(ws + M1_OFF);
    float* m2st  = (float*)(ws + M2_OFF);
    float* m2sst = (float*)(ws + M2S_OFF);
    unsigned int* counts = (unsigned int*)(ws + CNT_OFF);

    snn_prep<<<256, 256, 0, stream>>>(W1, W2, W2T, W1Tg, m1st, m2st, m2sst, counts);
    for (int s = 0; s < NSEG; ++s) {
        snn_cur1<<<2000, 256, 0, stream>>>(spikes, W1Tg, b1, CUR, s);
        snn_scan1<<<256, 256, 0, stream>>>(CUR, m1st, masks, counts, s);
        snn_cur2<<<16000, 256, 0, stream>>>(masks, W2T, b2, CUR, s);
        snn_scan2<<<256, 256, 0, stream>>>(CUR, m2st, m2sst, Wr, br, out, counts, s);
    }
    snn_finalize<<<1, 64, 0, stream>>>(counts, out);
}

// Round 12
// 853.914 us; speedup vs baseline: 1.1417x; 1.0474x over previous
//
#include <hip/hip_runtime.h>
#include <stdint.h>

#define TSTEPS 1000
#define NB 256
#define NF 64
#define NH 256   // H1 == H2 == 256
#define TSEG 250
#define NSEG 4   // 4 * 250 == 1000

// Workspace layout (bytes). CUR buffer is reused: A writes CUR1, B consumes
// it, C overwrites with CUR2, D consumes. Total ~74.9 MB.
#define CUR_BYTES ((size_t)TSEG * NB * NH * 4)          // 65,536,000
#define MSK_OFF   (CUR_BYTES)
#define MSK_BYTES ((size_t)TSTEPS * NB * 4 * 8)         // 8,192,000 (4 u64 per (t,b))
#define W2T_OFF   (MSK_OFF + MSK_BYTES)
#define W2T_BYTES ((size_t)NH * NH * 4)                 // 262,144
#define W1T_OFF   (W2T_OFF + W2T_BYTES)
#define W1T_BYTES ((size_t)NF * NH * 4)                 // 65,536
#define M1_OFF    (W1T_OFF + W1T_BYTES)
#define ST_BYTES  ((size_t)NB * NH * 4)                 // 262,144
#define M2_OFF    (M1_OFF + ST_BYTES)
#define M2S_OFF   (M2_OFF + ST_BYTES)
#define CNT_OFF   (M2S_OFF + ST_BYTES)

// Prep: W2T[h1][h2] transpose, W1Tg[f][h1] transpose, zero states/counters.
__global__ void snn_prep(const float* __restrict__ W1, const float* __restrict__ W2,
                         float* __restrict__ W2T, float* __restrict__ W1Tg,
                         float* __restrict__ m1st, float* __restrict__ m2st,
                         float* __restrict__ m2sst, unsigned int* __restrict__ counts) {
    int idx = blockIdx.x * 256 + threadIdx.x;            // [0, 65536)
    W2T[idx] = W2[(idx & 255) * 256 + (idx >> 8)];       // W2T[h1*256+h2] = W2[h2*256+h1]
    m1st[idx] = 0.f; m2st[idx] = 0.f; m2sst[idx] = 0.f;
    if (idx < NF * NH) W1Tg[(idx & 63) * 256 + (idx >> 6)] = W1[idx]; // W1Tg[f*256+h]=W1[h*64+f]
    if (idx < 2) counts[idx] = 0u;
}

// A: CUR1[t,b,h] = b1[h] + x[t,b,:]@W1[h,:] — fully parallel over (t,b).
// Sparse 4-chain ctz gather (f-quarters ascending, (a0+a1)+(a2+a3)) —
// bit-exact order match to all passing rounds.
__launch_bounds__(256)
__global__ void snn_cur1(const float* __restrict__ spikes,
                         const float* __restrict__ W1Tg,
                         const float* __restrict__ b1,
                         float* __restrict__ CUR, int s) {
    const int tid = threadIdx.x;
    const int lane = tid & 63, wv = tid >> 6;
    __shared__ float W1T[NF][NH];     // 64 KB; [f][h]
    for (int i = tid; i < NF * NH; i += 256) W1T[i >> 8][i & 255] = W1Tg[i];
    __syncthreads();

    const float4 b1v = *(const float4*)&b1[4 * lane];
    const int pbase = (blockIdx.x * 4 + wv) * 8;
    for (int k = 0; k < 8; ++k) {
        const int p = pbase + k;
        const int b = p & 255, tl = p >> 8;
        float xv = spikes[((size_t)(s * TSEG + tl) * NB + b) * NF + lane];
        unsigned long long xm = __ballot(xv > 0.f);
        unsigned m0 = (unsigned)(xm & 0xFFFFull);
        unsigned m1 = (unsigned)((xm >> 16) & 0xFFFFull);
        unsigned m2 = (unsigned)((xm >> 32) & 0xFFFFull);
        unsigned m3 = (unsigned)((xm >> 48) & 0xFFFFull);
        float a00 = 0.f, a10 = 0.f, a20 = 0.f, a30 = 0.f;
        float a01 = 0.f, a11 = 0.f, a21 = 0.f, a31 = 0.f;
        float a02 = 0.f, a12 = 0.f, a22 = 0.f, a32 = 0.f;
        float a03 = 0.f, a13 = 0.f, a23 = 0.f, a33 = 0.f;
        while (m0 | m1 | m2 | m3) {
            if (m0) { int f = __builtin_ctz(m0); m0 &= m0 - 1;
                float4 v = *(const float4*)&W1T[f][4 * lane];
                a00 += v.x; a10 += v.y; a20 += v.z; a30 += v.w; }
            if (m1) { int f = __builtin_ctz(m1) + 16; m1 &= m1 - 1;
                float4 v = *(const float4*)&W1T[f][4 * lane];
                a01 += v.x; a11 += v.y; a21 += v.z; a31 += v.w; }
            if (m2) { int f = __builtin_ctz(m2) + 32; m2 &= m2 - 1;
                float4 v = *(const float4*)&W1T[f][4 * lane];
                a02 += v.x; a12 += v.y; a22 += v.z; a32 += v.w; }
            if (m3) { int f = __builtin_ctz(m3) + 48; m3 &= m3 - 1;
                float4 v = *(const float4*)&W1T[f][4 * lane];
                a03 += v.x; a13 += v.y; a23 += v.z; a33 += v.w; }
        }
        float4 o;
        o.x = b1v.x + ((a00 + a01) + (a02 + a03));
        o.y = b1v.y + ((a10 + a11) + (a12 + a13));
        o.z = b1v.z + ((a20 + a21) + (a22 + a23));
        o.w = b1v.w + ((a30 + a31) + (a32 + a33));
        *(float4*)&CUR[((size_t)tl * NB + b) * NH + 4 * lane] = o;
    }
}

// B: serial mem1 scan (streaming). Thread=(b,h). BRANCHLESS body (round-11
// lesson: the `if (lane==0)` store split the unrolled loop into per-iteration
// basic blocks; the BB-local machine scheduler then couldn't batch loads ->
// 1 load in flight x ~900cyc x 250 = 83us. All 64 lanes store the identical
// mask value to the same address (one winner, deterministic) -> single-BB
// body; unroll 25 lets the scheduler put 25 loads in flight).
__launch_bounds__(256)
__global__ void snn_scan1(const float* __restrict__ CUR,
                          float* __restrict__ m1st,
                          unsigned long long* __restrict__ masks,
                          unsigned int* __restrict__ counts, int s) {
    const int b = blockIdx.x, h = threadIdx.x;
    const int lane = h & 63, wv = h >> 6;
    float mem1 = (s == 0) ? 0.f : m1st[b * NH + h];
    int cnt1 = 0;
    const float* cp = CUR + (size_t)b * NH + h;
    unsigned long long* mp = masks + ((size_t)(s * TSEG) * NB + b) * 4 + wv;
    #pragma unroll 25
    for (int tl = 0; tl < TSEG; ++tl) {
        float cur1 = cp[(size_t)tl * (NB * NH)];
        float reset1 = (mem1 > 1.f) ? 1.f : 0.f;
        mem1 = 0.8187307530779818f * mem1 + cur1 - reset1;   // beta1 = exp(-1/5)
        bool s1 = (mem1 - 1.f) > 0.f;
        cnt1 += (int)s1;
        unsigned long long sm = __ballot(s1);
        mp[(size_t)tl * (NB * 4)] = sm;   // all lanes, same addr, same value
    }
    m1st[b * NH + h] = mem1;
    for (int off = 32; off > 0; off >>= 1) cnt1 += __shfl_down(cnt1, off);
    if (lane == 0) atomicAdd(&counts[0], (unsigned)cnt1);
}

// C: CUR2[t,b,h2] = b2[h2] + sum over active h1 of W2T[h1][h2] — fully
// parallel over (t,b). 4 chains = the 4 h1-groups (ascending h1 within
// each, (q0+q1)+(q2+q3)) — exact consumer order. W2T rows are L2-resident.
__launch_bounds__(256)
__global__ void snn_cur2(const unsigned long long* __restrict__ masks,
                         const float* __restrict__ W2T,
                         const float* __restrict__ b2,
                         float* __restrict__ CUR, int s) {
    const int tid = threadIdx.x;
    const int lane = tid & 63, wv = tid >> 6;
    const int p = blockIdx.x * 4 + wv;
    const int b = p & 255, tl = p >> 8;
    const unsigned long long* mp = masks + ((size_t)(s * TSEG + tl) * NB + b) * 4;
    unsigned long long m0 = mp[0], m1 = mp[1], m2 = mp[2], m3 = mp[3];
    float q00 = 0.f, q10 = 0.f, q20 = 0.f, q30 = 0.f;
    float q01 = 0.f, q11 = 0.f, q21 = 0.f, q31 = 0.f;
    float q02 = 0.f, q12 = 0.f, q22 = 0.f, q32 = 0.f;
    float q03 = 0.f, q13 = 0.f, q23 = 0.f, q33 = 0.f;
    const float* W2l = W2T + 4 * lane;
    while (m0 | m1 | m2 | m3) {
        if (m0) { int j = __builtin_ctzll(m0); m0 &= m0 - 1;
            float4 v = *(const float4*)(W2l + ((size_t)j << 8));
            q00 += v.x; q10 += v.y; q20 += v.z; q30 += v.w; }
        if (m1) { int j = __builtin_ctzll(m1); m1 &= m1 - 1;
            float4 v = *(const float4*)(W2l + ((size_t)(64 + j) << 8));
            q01 += v.x; q11 += v.y; q21 += v.z; q31 += v.w; }
        if (m2) { int j = __builtin_ctzll(m2); m2 &= m2 - 1;
            float4 v = *(const float4*)(W2l + ((size_t)(128 + j) << 8));
            q02 += v.x; q12 += v.y; q22 += v.z; q32 += v.w; }
        if (m3) { int j = __builtin_ctzll(m3); m3 &= m3 - 1;
            float4 v = *(const float4*)(W2l + ((size_t)(192 + j) << 8));
            q03 += v.x; q13 += v.y; q23 += v.z; q33 += v.w; }
    }
    const float4 b2v = *(const float4*)&b2[4 * lane];
    float4 o;
    o.x = b2v.x + ((q00 + q01) + (q02 + q03));
    o.y = b2v.y + ((q10 + q11) + (q12 + q13));
    o.z = b2v.z + ((q20 + q21) + (q22 + q23));
    o.w = b2v.w + ((q30 + q31) + (q32 + q33));
    *(float4*)&CUR[((size_t)tl * NB + b) * NH + 4 * lane] = o;
}

// D: serial mem2 scan (streaming, branchless) + readout on the last segment.
__launch_bounds__(256)
__global__ void snn_scan2(const float* __restrict__ CUR,
                          float* __restrict__ m2st, float* __restrict__ m2sst,
                          const float* __restrict__ Wr, const float* __restrict__ br,
                          float* __restrict__ out, unsigned int* __restrict__ counts,
                          int s) {
    const int b = blockIdx.x, h = threadIdx.x;
    const int lane = h & 63, wv = h >> 6;
    __shared__ float rp0[4], rp1[4];
    float mem2 = (s == 0) ? 0.f : m2st[b * NH + h];
    float m2s  = (s == 0) ? 0.f : m2sst[b * NH + h];
    int cnt2 = 0;
    const float* cp = CUR + (size_t)b * NH + h;
    #pragma unroll 25
    for (int tl = 0; tl < TSEG; ++tl) {
        float cur2 = cp[(size_t)tl * (NB * NH)];
        float reset2 = (mem2 > 1.f) ? 1.f : 0.f;
        mem2 = 0.9048374180359595f * mem2 + cur2 - reset2;   // beta2 = exp(-1/10)
        bool s2 = (mem2 - 1.f) > 0.f;
        cnt2 += (int)s2;
        m2s += mem2;
    }
    for (int off = 32; off > 0; off >>= 1) cnt2 += __shfl_down(cnt2, off);
    if (lane == 0) atomicAdd(&counts[1], (unsigned)cnt2);
    if (s < NSEG - 1) {
        m2st[b * NH + h] = mem2;
        m2sst[b * NH + h] = m2s;
    } else {
        // readout: out[b,:] = (mem2_sum/T) @ Wr.T + br (r0-verified reduction)
        float v = m2s / 1000.0f;
        float p0 = v * Wr[h];
        float p1 = v * Wr[NH + h];
        for (int off = 32; off > 0; off >>= 1) {
            p0 += __shfl_down(p0, off);
            p1 += __shfl_down(p1, off);
        }
        if (lane == 0) { rp0[wv] = p0; rp1[wv] = p1; }
        __syncthreads();
        if (h == 0) {
            out[2 * b]     = ((rp0[0] + rp0[1]) + (rp0[2] + rp0[3])) + br[0];
            out[2 * b + 1] = ((rp1[0] + rp1[1]) + (rp1[2] + rp1[3])) + br[1];
        }
    }
}

__global__ void snn_finalize(const unsigned int* __restrict__ counts,
                             float* __restrict__ out) {
    if (threadIdx.x < 2)
        out[512 + threadIdx.x] = (float)counts[threadIdx.x] / 65536000.0f; // T*B*256
}

extern "C" void kernel_launch(void* const* d_in, const int* in_sizes, int n_in,
                              void* d_out, int out_size, void* d_ws, size_t ws_size,
                              hipStream_t stream) {
    const float* spikes = (const float*)d_in[0];
    const float* W1     = (const float*)d_in[1];
    const float* b1     = (const float*)d_in[2];
    const float* W2     = (const float*)d_in[3];
    const float* b2     = (const float*)d_in[4];
    const float* Wr     = (const float*)d_in[5];
    const float* br     = (const float*)d_in[6];
    float* out = (float*)d_out;

    char* ws = (char*)d_ws;
    float* CUR = (float*)ws;
    unsigned long long* masks = (unsigned long long*)(ws + MSK_OFF);
    float* W2T   = (float*)(ws + W2T_OFF);
    float* W1Tg  = (float*)(ws + W1T_OFF);
    float* m1st  = (float*)(ws + M1_OFF);
    float* m2st  = (float*)(ws + M2_OFF);
    float* m2sst = (float*)(ws + M2S_OFF);
    unsigned int* counts = (unsigned int*)(ws + CNT_OFF);

    snn_prep<<<256, 256, 0, stream>>>(W1, W2, W2T, W1Tg, m1st, m2st, m2sst, counts);
    for (int s = 0; s < NSEG; ++s) {
        snn_cur1<<<2000, 256, 0, stream>>>(spikes, W1Tg, b1, CUR, s);
        snn_scan1<<<256, 256, 0, stream>>>(CUR, m1st, masks, counts, s);
        snn_cur2<<<16000, 256, 0, stream>>>(masks, W2T, b2, CUR, s);
        snn_scan2<<<256, 256, 0, stream>>>(CUR, m2st, m2sst, Wr, br, out, counts, s);
    }
    snn_finalize<<<1, 64, 0, stream>>>(counts, out);
}

// Round 13
// 679.107 us; speedup vs baseline: 1.4356x; 1.2574x over previous
//
#include <hip/hip_runtime.h>
#include <stdint.h>

#define TSTEPS 1000
#define NB 256
#define NF 64
#define NH 256   // H1 == H2 == 256
#define TSEG 250
#define NSEG 4   // 4 * 250 == 1000
#define CHK 50   // scan staging chunk (5 per segment)

// Workspace layout (bytes). CUR buffer is reused: A writes CUR1, B consumes
// it, C overwrites with CUR2, D consumes. Total ~74.9 MB.
#define CUR_BYTES ((size_t)TSEG * NB * NH * 4)          // 65,536,000
#define MSK_OFF   (CUR_BYTES)
#define MSK_BYTES ((size_t)TSTEPS * NB * 4 * 8)         // 8,192,000 (4 u64 per (t,b))
#define W2T_OFF   (MSK_OFF + MSK_BYTES)
#define W2T_BYTES ((size_t)NH * NH * 4)                 // 262,144
#define W1T_OFF   (W2T_OFF + W2T_BYTES)
#define W1T_BYTES ((size_t)NF * NH * 4)                 // 65,536
#define M1_OFF    (W1T_OFF + W1T_BYTES)
#define ST_BYTES  ((size_t)NB * NH * 4)                 // 262,144
#define M2_OFF    (M1_OFF + ST_BYTES)
#define M2S_OFF   (M2_OFF + ST_BYTES)
#define CNT_OFF   (M2S_OFF + ST_BYTES)

// Async global->LDS DMA (rounds 10/12 lesson: loads feeding a serial chain
// are never kept in flight by the scheduler — VGPR=8, one load per ~900cyc.
// global_load_lds has no dest VGPR, so 50 issued stages = 50 requests in the
// vmcnt queue; __syncthreads() drains them once per chunk).
__device__ __forceinline__ void gload_lds4(const float* g, float* l) {
    __builtin_amdgcn_global_load_lds(
        (const __attribute__((address_space(1))) void*)g,
        (__attribute__((address_space(3))) void*)l, 4, 0, 0);
}

// Prep: W2T[h1][h2] transpose, W1Tg[f][h1] transpose, zero states/counters.
__global__ void snn_prep(const float* __restrict__ W1, const float* __restrict__ W2,
                         float* __restrict__ W2T, float* __restrict__ W1Tg,
                         float* __restrict__ m1st, float* __restrict__ m2st,
                         float* __restrict__ m2sst, unsigned int* __restrict__ counts) {
    int idx = blockIdx.x * 256 + threadIdx.x;            // [0, 65536)
    W2T[idx] = W2[(idx & 255) * 256 + (idx >> 8)];       // W2T[h1*256+h2] = W2[h2*256+h1]
    m1st[idx] = 0.f; m2st[idx] = 0.f; m2sst[idx] = 0.f;
    if (idx < NF * NH) W1Tg[(idx & 63) * 256 + (idx >> 6)] = W1[idx]; // W1Tg[f*256+h]=W1[h*64+f]
    if (idx < 2) counts[idx] = 0u;
}

// A: CUR1[t,b,h] = b1[h] + x[t,b,:]@W1[h,:] — fully parallel over (t,b).
// Sparse 4-chain ctz gather (f-quarters ascending, (a0+a1)+(a2+a3)) —
// bit-exact order match to all passing rounds.
__launch_bounds__(256)
__global__ void snn_cur1(const float* __restrict__ spikes,
                         const float* __restrict__ W1Tg,
                         const float* __restrict__ b1,
                         float* __restrict__ CUR, int s) {
    const int tid = threadIdx.x;
    const int lane = tid & 63, wv = tid >> 6;
    __shared__ float W1T[NF][NH];     // 64 KB; [f][h]
    for (int i = tid; i < NF * NH; i += 256) W1T[i >> 8][i & 255] = W1Tg[i];
    __syncthreads();

    const float4 b1v = *(const float4*)&b1[4 * lane];
    const int pbase = (blockIdx.x * 4 + wv) * 8;
    for (int k = 0; k < 8; ++k) {
        const int p = pbase + k;
        const int b = p & 255, tl = p >> 8;
        float xv = spikes[((size_t)(s * TSEG + tl) * NB + b) * NF + lane];
        unsigned long long xm = __ballot(xv > 0.f);
        unsigned m0 = (unsigned)(xm & 0xFFFFull);
        unsigned m1 = (unsigned)((xm >> 16) & 0xFFFFull);
        unsigned m2 = (unsigned)((xm >> 32) & 0xFFFFull);
        unsigned m3 = (unsigned)((xm >> 48) & 0xFFFFull);
        float a00 = 0.f, a10 = 0.f, a20 = 0.f, a30 = 0.f;
        float a01 = 0.f, a11 = 0.f, a21 = 0.f, a31 = 0.f;
        float a02 = 0.f, a12 = 0.f, a22 = 0.f, a32 = 0.f;
        float a03 = 0.f, a13 = 0.f, a23 = 0.f, a33 = 0.f;
        while (m0 | m1 | m2 | m3) {
            if (m0) { int f = __builtin_ctz(m0); m0 &= m0 - 1;
                float4 v = *(const float4*)&W1T[f][4 * lane];
                a00 += v.x; a10 += v.y; a20 += v.z; a30 += v.w; }
            if (m1) { int f = __builtin_ctz(m1) + 16; m1 &= m1 - 1;
                float4 v = *(const float4*)&W1T[f][4 * lane];
                a01 += v.x; a11 += v.y; a21 += v.z; a31 += v.w; }
            if (m2) { int f = __builtin_ctz(m2) + 32; m2 &= m2 - 1;
                float4 v = *(const float4*)&W1T[f][4 * lane];
                a02 += v.x; a12 += v.y; a22 += v.z; a32 += v.w; }
            if (m3) { int f = __builtin_ctz(m3) + 48; m3 &= m3 - 1;
                float4 v = *(const float4*)&W1T[f][4 * lane];
                a03 += v.x; a13 += v.y; a23 += v.z; a33 += v.w; }
        }
        float4 o;
        o.x = b1v.x + ((a00 + a01) + (a02 + a03));
        o.y = b1v.y + ((a10 + a11) + (a12 + a13));
        o.z = b1v.z + ((a20 + a21) + (a22 + a23));
        o.w = b1v.w + ((a30 + a31) + (a32 + a33));
        *(float4*)&CUR[((size_t)tl * NB + b) * NH + 4 * lane] = o;
    }
}

// B: serial mem1 scan. Per 50-step chunk: async-stage CUR rows into LDS via
// global_load_lds (wave w stages its quarter of each row; LDS dst is
// wave-uniform base + lane*4 as the HW requires), __syncthreads() drains
// vmcnt once, then the recurrence runs from LDS (conflict-free: 64
// consecutive lanes = 2 lanes/bank).
__launch_bounds__(256)
__global__ void snn_scan1(const float* __restrict__ CUR,
                          float* __restrict__ m1st,
                          unsigned long long* __restrict__ masks,
                          unsigned int* __restrict__ counts, int s) {
    const int b = blockIdx.x, h = threadIdx.x;
    const int lane = h & 63, wv = h >> 6;
    __shared__ float xs[CHK][NH];     // 51.2 KB
    float mem1 = (s == 0) ? 0.f : m1st[b * NH + h];
    int cnt1 = 0;
    unsigned long long* mp = masks + ((size_t)(s * TSEG) * NB + b) * 4 + wv;

    for (int ck = 0; ck < TSEG / CHK; ++ck) {
        const int t0 = ck * CHK;
        const float* gsrc = CUR + ((size_t)t0 * NB + b) * NH + (wv << 6) + lane;
        #pragma unroll
        for (int r = 0; r < CHK; ++r)
            gload_lds4(gsrc + (size_t)r * (NB * NH), &xs[r][wv << 6]);
        __syncthreads();   // drains vmcnt: all 50 stages landed; LDS visible
        for (int r = 0; r < CHK; ++r) {
            float cur1 = xs[r][h];
            float reset1 = (mem1 > 1.f) ? 1.f : 0.f;
            mem1 = 0.8187307530779818f * mem1 + cur1 - reset1;  // beta1=exp(-1/5)
            bool s1 = (mem1 - 1.f) > 0.f;
            cnt1 += (int)s1;
            unsigned long long sm = __ballot(s1);
            mp[(size_t)(t0 + r) * (NB * 4)] = sm;  // all lanes, same addr/value
        }
        __syncthreads();   // chunk fully consumed before next overwrite
    }
    m1st[b * NH + h] = mem1;
    for (int off = 32; off > 0; off >>= 1) cnt1 += __shfl_down(cnt1, off);
    if (lane == 0) atomicAdd(&counts[0], (unsigned)cnt1);
}

// C: CUR2[t,b,h2] = b2[h2] + sum over active h1 of W2T[h1][h2] — fully
// parallel over (t,b). 4 chains = the 4 h1-groups (ascending h1 within
// each, (q0+q1)+(q2+q3)) — exact consumer order. W2T rows are L2-resident.
__launch_bounds__(256)
__global__ void snn_cur2(const unsigned long long* __restrict__ masks,
                         const float* __restrict__ W2T,
                         const float* __restrict__ b2,
                         float* __restrict__ CUR, int s) {
    const int tid = threadIdx.x;
    const int lane = tid & 63, wv = tid >> 6;
    const int p = blockIdx.x * 4 + wv;
    const int b = p & 255, tl = p >> 8;
    const unsigned long long* mp = masks + ((size_t)(s * TSEG + tl) * NB + b) * 4;
    unsigned long long m0 = mp[0], m1 = mp[1], m2 = mp[2], m3 = mp[3];
    float q00 = 0.f, q10 = 0.f, q20 = 0.f, q30 = 0.f;
    float q01 = 0.f, q11 = 0.f, q21 = 0.f, q31 = 0.f;
    float q02 = 0.f, q12 = 0.f, q22 = 0.f, q32 = 0.f;
    float q03 = 0.f, q13 = 0.f, q23 = 0.f, q33 = 0.f;
    const float* W2l = W2T + 4 * lane;
    while (m0 | m1 | m2 | m3) {
        if (m0) { int j = __builtin_ctzll(m0); m0 &= m0 - 1;
            float4 v = *(const float4*)(W2l + ((size_t)j << 8));
            q00 += v.x; q10 += v.y; q20 += v.z; q30 += v.w; }
        if (m1) { int j = __builtin_ctzll(m1); m1 &= m1 - 1;
            float4 v = *(const float4*)(W2l + ((size_t)(64 + j) << 8));
            q01 += v.x; q11 += v.y; q21 += v.z; q31 += v.w; }
        if (m2) { int j = __builtin_ctzll(m2); m2 &= m2 - 1;
            float4 v = *(const float4*)(W2l + ((size_t)(128 + j) << 8));
            q02 += v.x; q12 += v.y; q22 += v.z; q32 += v.w; }
        if (m3) { int j = __builtin_ctzll(m3); m3 &= m3 - 1;
            float4 v = *(const float4*)(W2l + ((size_t)(192 + j) << 8));
            q03 += v.x; q13 += v.y; q23 += v.z; q33 += v.w; }
    }
    const float4 b2v = *(const float4*)&b2[4 * lane];
    float4 o;
    o.x = b2v.x + ((q00 + q01) + (q02 + q03));
    o.y = b2v.y + ((q10 + q11) + (q12 + q13));
    o.z = b2v.z + ((q20 + q21) + (q22 + q23));
    o.w = b2v.w + ((q30 + q31) + (q32 + q33));
    *(float4*)&CUR[((size_t)tl * NB + b) * NH + 4 * lane] = o;
}

// D: serial mem2 scan (same async-LDS staging) + readout on last segment.
__launch_bounds__(256)
__global__ void snn_scan2(const float* __restrict__ CUR,
                          float* __restrict__ m2st, float* __restrict__ m2sst,
                          const float* __restrict__ Wr, const float* __restrict__ br,
                          float* __restrict__ out, unsigned int* __restrict__ counts,
                          int s) {
    const int b = blockIdx.x, h = threadIdx.x;
    const int lane = h & 63, wv = h >> 6;
    __shared__ float xs[CHK][NH];     // 51.2 KB
    __shared__ float rp0[4], rp1[4];
    float mem2 = (s == 0) ? 0.f : m2st[b * NH + h];
    float m2s  = (s == 0) ? 0.f : m2sst[b * NH + h];
    int cnt2 = 0;

    for (int ck = 0; ck < TSEG / CHK; ++ck) {
        const int t0 = ck * CHK;
        const float* gsrc = CUR + ((size_t)t0 * NB + b) * NH + (wv << 6) + lane;
        #pragma unroll
        for (int r = 0; r < CHK; ++r)
            gload_lds4(gsrc + (size_t)r * (NB * NH), &xs[r][wv << 6]);
        __syncthreads();
        for (int r = 0; r < CHK; ++r) {
            float cur2 = xs[r][h];
            float reset2 = (mem2 > 1.f) ? 1.f : 0.f;
            mem2 = 0.9048374180359595f * mem2 + cur2 - reset2;  // beta2=exp(-1/10)
            bool s2 = (mem2 - 1.f) > 0.f;
            cnt2 += (int)s2;
            m2s += mem2;
        }
        __syncthreads();
    }
    for (int off = 32; off > 0; off >>= 1) cnt2 += __shfl_down(cnt2, off);
    if (lane == 0) atomicAdd(&counts[1], (unsigned)cnt2);
    if (s < NSEG - 1) {
        m2st[b * NH + h] = mem2;
        m2sst[b * NH + h] = m2s;
    } else {
        // readout: out[b,:] = (mem2_sum/T) @ Wr.T + br (r0-verified reduction)
        float v = m2s / 1000.0f;
        float p0 = v * Wr[h];
        float p1 = v * Wr[NH + h];
        for (int off = 32; off > 0; off >>= 1) {
            p0 += __shfl_down(p0, off);
            p1 += __shfl_down(p1, off);
        }
        if (lane == 0) { rp0[wv] = p0; rp1[wv] = p1; }
        __syncthreads();
        if (h == 0) {
            out[2 * b]     = ((rp0[0] + rp0[1]) + (rp0[2] + rp0[3])) + br[0];
            out[2 * b + 1] = ((rp1[0] + rp1[1]) + (rp1[2] + rp1[3])) + br[1];
        }
    }
}

__global__ void snn_finalize(const unsigned int* __restrict__ counts,
                             float* __restrict__ out) {
    if (threadIdx.x < 2)
        out[512 + threadIdx.x] = (float)counts[threadIdx.x] / 65536000.0f; // T*B*256
}

extern "C" void kernel_launch(void* const* d_in, const int* in_sizes, int n_in,
                              void* d_out, int out_size, void* d_ws, size_t ws_size,
                              hipStream_t stream) {
    const float* spikes = (const float*)d_in[0];
    const float* W1     = (const float*)d_in[1];
    const float* b1     = (const float*)d_in[2];
    const float* W2     = (const float*)d_in[3];
    const float* b2     = (const float*)d_in[4];
    const float* Wr     = (const float*)d_in[5];
    const float* br     = (const float*)d_in[6];
    float* out = (float*)d_out;

    char* ws = (char*)d_ws;
    float* CUR = (float*)ws;
    unsigned long long* masks = (unsigned long long*)(ws + MSK_OFF);
    float* W2T   = (float*)(ws + W2T_OFF);
    float* W1Tg  = (float*)(ws + W1T_OFF);
    float* m1st  = (float*)(ws + M1_OFF);
    float* m2st  = (float*)(ws + M2_OFF);
    float* m2sst = (float*)(ws + M2S_OFF);
    unsigned int* counts = (unsigned int*)(ws + CNT_OFF);

    snn_prep<<<256, 256, 0, stream>>>(W1, W2, W2T, W1Tg, m1st, m2st, m2sst, counts);
    for (int s = 0; s < NSEG; ++s) {
        snn_cur1<<<2000, 256, 0, stream>>>(spikes, W1Tg, b1, CUR, s);
        snn_scan1<<<256, 256, 0, stream>>>(CUR, m1st, masks, counts, s);
        snn_cur2<<<16000, 256, 0, stream>>>(masks, W2T, b2, CUR, s);
        snn_scan2<<<256, 256, 0, stream>>>(CUR, m2st, m2sst, Wr, br, out, counts, s);
    }
    snn_finalize<<<1, 64, 0, stream>>>(counts, out);
}